// Round 4
// baseline (284.302 us; speedup 1.0000x reference)
//
#include <hip/hip_runtime.h>
#include <hip/hip_bf16.h>
#include <math.h>

#define NN 2048
#define DA 256
#define DK 64
#define DG 64

typedef float f32x4 __attribute__((ext_vector_type(4)));

// Allreduce-sum across each 16-lane row, pure VALU (DPP), no LDS pipe.
// quad_perm xor1 (0xB1), quad_perm xor2 (0x4E), row_ror:4 (0x124), row_ror:8 (0x128)
// After these 4 steps ALL 16 lanes hold the row sum.
__device__ __forceinline__ float dpp_reduce16(float x) {
  int t;
  t = __builtin_amdgcn_update_dpp(0, __float_as_int(x), 0xB1, 0xF, 0xF, true);
  x += __int_as_float(t);
  t = __builtin_amdgcn_update_dpp(0, __float_as_int(x), 0x4E, 0xF, 0xF, true);
  x += __int_as_float(t);
  t = __builtin_amdgcn_update_dpp(0, __float_as_int(x), 0x124, 0xF, 0xF, true);
  x += __int_as_float(t);
  t = __builtin_amdgcn_update_dpp(0, __float_as_int(x), 0x128, 0xF, 0xF, true);
  x += __int_as_float(t);
  return x;
}

// One block per row m: stage f_a row in LDS, 192 threads each compute one
// output element of {w_k, w_q, w_v}.
__global__ __launch_bounds__(256) void proj_kernel(
    const float* __restrict__ fa,
    const float* __restrict__ WKw, const float* __restrict__ WKb,
    const float* __restrict__ WQw, const float* __restrict__ WQb,
    const float* __restrict__ WVw, const float* __restrict__ WVb,
    float* __restrict__ wk, float* __restrict__ wq, float* __restrict__ wv)
{
  __shared__ float s_fa[DA];
  const int m = blockIdx.x, tid = threadIdx.x;
  s_fa[tid] = fa[(size_t)m * DA + tid];
  __syncthreads();
  if (tid < 192) {
    const int o = tid >> 6, k = tid & 63;
    const float* W = (o == 0 ? WKw : (o == 1 ? WQw : WVw)) + (size_t)k * DA;
    const float* B = (o == 0 ? WKb : (o == 1 ? WQb : WVb));
    float acc = B[k];
    const float4* W4 = (const float4*)W;
    const float4* F4 = (const float4*)s_fa;
    #pragma unroll 8
    for (int c = 0; c < DA / 4; ++c) {
      float4 w4 = W4[c], f4 = F4[c];
      acc = fmaf(w4.x, f4.x, acc); acc = fmaf(w4.y, f4.y, acc);
      acc = fmaf(w4.z, f4.z, acc); acc = fmaf(w4.w, f4.w, acc);
    }
    float* dst = (o == 0 ? wk : (o == 1 ? wq : wv));
    dst[(size_t)m * DK + k] = acc;
  }
}

// One block (256 threads = 4 waves) per output row m.
// Single streaming loop with online softmax: per 4-n iteration each wave
// computes logits (coalesced pe+wq loads, DPP allreduce so all 16 lanes of a
// sub-row hold the logit), then online-updates (m, l, acc[f32x4 slice]) with
// the coalesced wv load. No big LDS buffer, one barrier, HBM never idles.
__global__ __launch_bounds__(256) void fused_kernel(
    const float* __restrict__ pe,
    const float* __restrict__ wgw, const float* __restrict__ wgb,
    const float* __restrict__ wk, const float* __restrict__ wq,
    const float* __restrict__ wv,
    float* __restrict__ out)
{
  __shared__ float s_wacc[4][DK];   // per-wave acc (in wave's own max frame)
  __shared__ float s_wm[4], s_wl[4];

  const int m = blockIdx.x, tid = threadIdx.x;
  const int wave = tid >> 6, lane = tid & 63;
  const int sub = lane >> 4;             // n within the 4-row block
  const int c4  = lane & 15;             // float4 chunk within 64 floats

  // loop-invariant per-lane slices
  const f32x4 wg4 = ((const f32x4*)wgw)[c4];
  const f32x4 wk4 = ((const f32x4*)(wk + (size_t)m * DK))[c4];
  const float gb = wgb[0];

  float om = -INFINITY;                  // running max for this sub-row stripe
  float ol = 0.f;                        // running sum
  f32x4 acc = {0.f, 0.f, 0.f, 0.f};      // running value-acc, dims [4c4..4c4+4)

  const int n0 = wave * (NN / 4);
  #pragma unroll 2
  for (int it = 0; it < (NN / 4) / 4; ++it) {   // 128 iters, 4 n's each
    const int nb = n0 + it * 4;
    const f32x4 p = __builtin_nontemporal_load(
        (const f32x4*)(pe + ((size_t)m * NN + nb) * DG) + lane);
    const f32x4 q = ((const f32x4*)(wq + (size_t)nb * DK))[lane];
    const f32x4 v = ((const f32x4*)(wv + (size_t)(nb + sub) * DK))[c4];

    float dg = p.x * wg4.x, dq = q.x * wk4.x;
    dg = fmaf(p.y, wg4.y, dg); dq = fmaf(q.y, wk4.y, dq);
    dg = fmaf(p.z, wg4.z, dg); dq = fmaf(q.z, wk4.z, dq);
    dg = fmaf(p.w, wg4.w, dg); dq = fmaf(q.w, wk4.w, dq);
    dg = dpp_reduce16(dg);
    dq = dpp_reduce16(dq);

    // relu -> clip(1e-6) -> log  ==  log(max(x, 1e-6))
    const float logit = __logf(fmaxf(dg + gb, 1e-6f)) + dq * 0.125f;

    // online softmax update (uniform across the 16 lanes of this sub-row)
    const float mn = fmaxf(om, logit);
    const float scale = __expf(om - mn);      // 1 when max unchanged; 0 first iter
    const float pr = __expf(logit - mn);
    ol = fmaf(ol, scale, pr);
    acc.x = fmaf(acc.x, scale, pr * v.x);
    acc.y = fmaf(acc.y, scale, pr * v.y);
    acc.z = fmaf(acc.z, scale, pr * v.z);
    acc.w = fmaf(acc.w, scale, pr * v.w);
    om = mn;
  }

  // ---- combine the 4 sub-row stripes within the wave (lane bits 4,5) ----
  float M = fmaxf(om, __shfl_xor(om, 16, 64));
  M = fmaxf(M, __shfl_xor(M, 32, 64));
  const float f = __expf(om - M);
  ol *= f;
  acc.x *= f; acc.y *= f; acc.z *= f; acc.w *= f;
  ol    += __shfl_xor(ol, 16, 64);    ol    += __shfl_xor(ol, 32, 64);
  acc.x += __shfl_xor(acc.x, 16, 64); acc.x += __shfl_xor(acc.x, 32, 64);
  acc.y += __shfl_xor(acc.y, 16, 64); acc.y += __shfl_xor(acc.y, 32, 64);
  acc.z += __shfl_xor(acc.z, 16, 64); acc.z += __shfl_xor(acc.z, 32, 64);
  acc.w += __shfl_xor(acc.w, 16, 64); acc.w += __shfl_xor(acc.w, 32, 64);

  if (lane < 16) {                       // sub==0 slice holds the wave totals
    ((f32x4*)s_wacc[wave])[lane] = acc;
    if (lane == 0) { s_wm[wave] = M; s_wl[wave] = ol; }
  }
  __syncthreads();

  // ---- combine the 4 waves ----
  if (tid < DK) {
    const float Mg = fmaxf(fmaxf(s_wm[0], s_wm[1]), fmaxf(s_wm[2], s_wm[3]));
    float L = 0.f, r = 0.f;
    #pragma unroll
    for (int w = 0; w < 4; ++w) {
      const float fw = __expf(s_wm[w] - Mg);
      L = fmaf(s_wl[w], fw, L);
      r = fmaf(s_wacc[w][tid], fw, r);
    }
    out[(size_t)m * DK + tid] = r / L;
  }
}

extern "C" void kernel_launch(void* const* d_in, const int* in_sizes, int n_in,
                              void* d_out, int out_size, void* d_ws, size_t ws_size,
                              hipStream_t stream) {
  const float* fa  = (const float*)d_in[0];
  const float* pe  = (const float*)d_in[1];
  const float* wgw = (const float*)d_in[2];
  const float* wgb = (const float*)d_in[3];
  const float* wkw = (const float*)d_in[4];
  const float* wkb = (const float*)d_in[5];
  const float* wqw = (const float*)d_in[6];
  const float* wqb = (const float*)d_in[7];
  const float* wvw = (const float*)d_in[8];
  const float* wvb = (const float*)d_in[9];
  float* out = (float*)d_out;

  float* wk = (float*)d_ws;          // [NN, DK]
  float* wq = wk + (size_t)NN * DK;  // [NN, DK]
  float* wv = wq + (size_t)NN * DK;  // [NN, DK]

  proj_kernel<<<NN, 256, 0, stream>>>(fa, wkw, wkb, wqw, wqb, wvw, wvb, wk, wq, wv);
  fused_kernel<<<NN, 256, 0, stream>>>(pe, wgw, wgb, wk, wq, wv, out);
}